// Round 1
// baseline (765.326 us; speedup 1.0000x reference)
//
#include <hip/hip_runtime.h>

// FeatureTexel: bilinear gather from 100000x16x9x9 fp32 atlas.
// One thread computes 4 output channels for one (v,b) sample.
// Memory-bound: random ~2KB-granule gathers from a 518MB atlas (> L3).

constexpr int FD = 16;
constexpr int FS = 9;
constexpr int NSAMP = 65536 * 8;          // NV * NB
constexpr int CH_PER_THREAD = 4;
constexpr int THREADS_TOTAL = NSAMP * (FD / CH_PER_THREAD);  // 2,097,152
constexpr int BLOCK = 256;

__global__ __launch_bounds__(BLOCK) void FeatureTexel_kernel(
    const float2* __restrict__ x,
    const int*    __restrict__ inds,
    const float*  __restrict__ ft,
    float4*       __restrict__ out)
{
    int tid = blockIdx.x * BLOCK + threadIdx.x;
    int s  = tid >> 2;          // sample index
    int c0 = (tid & 3) * 4;     // first channel of this thread's group

    float2 xy = x[s];
    int ind   = inds[s];

    const float fsm1 = (float)(FS - 1);   // 8.0
    float gx = fminf(fmaxf((xy.x + 1.0f) * 0.5f * fsm1, 0.0f), fsm1);
    float gy = fminf(fmaxf((xy.y + 1.0f) * 0.5f * fsm1, 0.0f), fsm1);

    int x0 = (int)floorf(gx);
    int y0 = (int)floorf(gy);
    // Clamp so x0+1 / y0+1 stay in-bounds; wx/wy absorb the shift so the
    // result is value-identical to the reference (incl. gx==8 boundary).
    x0 = min(x0, FS - 2);
    y0 = min(y0, FS - 2);
    float wx = gx - (float)x0;
    float wy = gy - (float)y0;

    float w00 = (1.0f - wx) * (1.0f - wy);
    float w01 = wx * (1.0f - wy);
    float w10 = (1.0f - wx) * wy;
    float w11 = wx * wy;

    const float* base = ft + (size_t)ind * (FD * FS * FS)
                           + (size_t)c0 * (FS * FS)
                           + y0 * FS + x0;

    float r[CH_PER_THREAD];
    #pragma unroll
    for (int i = 0; i < CH_PER_THREAD; ++i) {
        const float* p = base + i * (FS * FS);
        float v00 = p[0];
        float v01 = p[1];
        float v10 = p[FS];
        float v11 = p[FS + 1];
        r[i] = v00 * w00 + v01 * w01 + v10 * w10 + v11 * w11;
    }

    out[tid] = make_float4(r[0], r[1], r[2], r[3]);
}

extern "C" void kernel_launch(void* const* d_in, const int* in_sizes, int n_in,
                              void* d_out, int out_size, void* d_ws, size_t ws_size,
                              hipStream_t stream) {
    const float2* x    = (const float2*)d_in[0];
    const int*    inds = (const int*)d_in[1];
    const float*  ft   = (const float*)d_in[2];
    float4*       out  = (float4*)d_out;

    FeatureTexel_kernel<<<THREADS_TOTAL / BLOCK, BLOCK, 0, stream>>>(x, inds, ft, out);
}

// Round 2
// 736.691 us; speedup vs baseline: 1.0389x; 1.0389x over previous
//
#include <hip/hip_runtime.h>

// FeatureTexel: bilinear gather from 100000x16x9x9 fp32 atlas (518 MB > L3).
// Round 2: counting-sort samples by atlas index, then gather in sorted order.
// Converts fully-random DRAM gathers (~1 TB/s effective) into an ascending,
// duplicate-coalesced sweep of the atlas (L2 hits for the avg 5.24x index
// reuse, DRAM row-hit friendly).

constexpr int FD = 16;
constexpr int FS = 9;
constexpr int NSAMP = 65536 * 8;          // 524288 samples
constexpr int NUM_ATLAS = 100000;
constexpr int BLOCK = 256;

constexpr int SCAN_CHUNK = 1024;                                   // elems per scan block
constexpr int NUM_SCAN_BLOCKS = (NUM_ATLAS + SCAN_CHUNK - 1) / SCAN_CHUNK;  // 98
constexpr int PARTIALS_PAD = 128;

// ws layout (ints): [hist NUM_ATLAS][partials PARTIALS_PAD][offsets NUM_ATLAS][order NSAMP]
__global__ __launch_bounds__(BLOCK) void hist_kernel(const int* __restrict__ inds,
                                                     int* __restrict__ hist) {
    int i = blockIdx.x * BLOCK + threadIdx.x;
    if (i < NSAMP) atomicAdd(&hist[inds[i]], 1);
}

__global__ __launch_bounds__(BLOCK) void scanA_kernel(const int* __restrict__ hist,
                                                      int* __restrict__ offsets,
                                                      int* __restrict__ partials) {
    __shared__ int lds[BLOCK];
    int t = threadIdx.x;
    int base = blockIdx.x * SCAN_CHUNK + t * 4;
    int v[4];
    #pragma unroll
    for (int j = 0; j < 4; ++j) v[j] = (base + j < NUM_ATLAS) ? hist[base + j] : 0;
    int sum = v[0] + v[1] + v[2] + v[3];
    lds[t] = sum;
    __syncthreads();
    // Hillis-Steele inclusive scan over 256 thread-sums
    for (int off = 1; off < BLOCK; off <<= 1) {
        int add = (t >= off) ? lds[t - off] : 0;
        __syncthreads();
        lds[t] += add;
        __syncthreads();
    }
    int incl = lds[t];
    int excl = incl - sum;
    if (t == BLOCK - 1) partials[blockIdx.x] = incl;
    int run = excl;
    #pragma unroll
    for (int j = 0; j < 4; ++j) {
        if (base + j < NUM_ATLAS) offsets[base + j] = run;
        run += v[j];
    }
}

__global__ void scanB_kernel(int* __restrict__ partials) {
    if (threadIdx.x == 0) {
        int run = 0;
        for (int i = 0; i < NUM_SCAN_BLOCKS; ++i) {
            int v = partials[i];
            partials[i] = run;
            run += v;
        }
    }
}

__global__ __launch_bounds__(BLOCK) void scanC_kernel(int* __restrict__ offsets,
                                                      const int* __restrict__ partials) {
    int i = blockIdx.x * BLOCK + threadIdx.x;
    if (i < NUM_ATLAS) offsets[i] += partials[i / SCAN_CHUNK];
}

__global__ __launch_bounds__(BLOCK) void scatter_kernel(const int* __restrict__ inds,
                                                        int* __restrict__ offsets,
                                                        int* __restrict__ order) {
    int i = blockIdx.x * BLOCK + threadIdx.x;
    if (i < NSAMP) {
        int ind = inds[i];
        int pos = atomicAdd(&offsets[ind], 1);
        order[pos] = i;
    }
}

__global__ __launch_bounds__(BLOCK) void gather_kernel(
    const float2* __restrict__ x,
    const int*    __restrict__ inds,
    const float*  __restrict__ ft,
    const int*    __restrict__ order,
    float4*       __restrict__ out)
{
    int tid = blockIdx.x * BLOCK + threadIdx.x;
    int s = order[tid >> 2];        // sorted sample id (4 lanes broadcast)
    int c0 = (tid & 3) * 4;         // first channel of this thread's group

    float2 xy = x[s];
    int ind   = inds[s];

    const float fsm1 = (float)(FS - 1);   // 8.0
    float gx = fminf(fmaxf((xy.x + 1.0f) * 0.5f * fsm1, 0.0f), fsm1);
    float gy = fminf(fmaxf((xy.y + 1.0f) * 0.5f * fsm1, 0.0f), fsm1);

    int x0 = (int)floorf(gx);
    int y0 = (int)floorf(gy);
    x0 = min(x0, FS - 2);
    y0 = min(y0, FS - 2);
    float wx = gx - (float)x0;
    float wy = gy - (float)y0;

    float w00 = (1.0f - wx) * (1.0f - wy);
    float w01 = wx * (1.0f - wy);
    float w10 = (1.0f - wx) * wy;
    float w11 = wx * wy;

    const float* base = ft + (size_t)ind * (FD * FS * FS)
                           + (size_t)c0 * (FS * FS)
                           + y0 * FS + x0;

    float r[4];
    #pragma unroll
    for (int i = 0; i < 4; ++i) {
        const float* p = base + i * (FS * FS);
        float v00 = p[0];
        float v01 = p[1];
        float v10 = p[FS];
        float v11 = p[FS + 1];
        r[i] = v00 * w00 + v01 * w01 + v10 * w10 + v11 * w11;
    }

    out[(size_t)s * 4 + (tid & 3)] = make_float4(r[0], r[1], r[2], r[3]);
}

extern "C" void kernel_launch(void* const* d_in, const int* in_sizes, int n_in,
                              void* d_out, int out_size, void* d_ws, size_t ws_size,
                              hipStream_t stream) {
    const float2* x    = (const float2*)d_in[0];
    const int*    inds = (const int*)d_in[1];
    const float*  ft   = (const float*)d_in[2];
    float4*       out  = (float4*)d_out;

    int* ws       = (int*)d_ws;
    int* hist     = ws;
    int* partials = hist + NUM_ATLAS;
    int* offsets  = partials + PARTIALS_PAD;
    int* order    = offsets + NUM_ATLAS;

    // zero hist + partials (ws is poisoned to 0xAA before every timed call)
    hipMemsetAsync(hist, 0, (size_t)(NUM_ATLAS + PARTIALS_PAD) * sizeof(int), stream);

    hist_kernel<<<(NSAMP + BLOCK - 1) / BLOCK, BLOCK, 0, stream>>>(inds, hist);
    scanA_kernel<<<NUM_SCAN_BLOCKS, BLOCK, 0, stream>>>(hist, offsets, partials);
    scanB_kernel<<<1, 64, 0, stream>>>(partials);
    scanC_kernel<<<(NUM_ATLAS + BLOCK - 1) / BLOCK, BLOCK, 0, stream>>>(offsets, partials);
    scatter_kernel<<<(NSAMP + BLOCK - 1) / BLOCK, BLOCK, 0, stream>>>(inds, offsets, order);

    int gather_threads = NSAMP * 4;   // 4 channel-groups per sample
    gather_kernel<<<gather_threads / BLOCK, BLOCK, 0, stream>>>(x, inds, ft, order, out);
}